// Round 4
// baseline (97.444 us; speedup 1.0000x reference)
//
#include <hip/hip_runtime.h>
#include <cmath>

// JPEG layer, fully fused, one wave per 16x16 tile.
// Lane (g,p): g = lane>>3 (block slot), p = lane&7 (row).
//   g 0..3 : Y 8x8 blocks (pixels loaded straight into registers)
//   g 4,5  : Cb / Cr blocks (staged through a tiny per-wave LDS buffer)
//   g 6,7  : ride along on the transform (masked from rescue/stores)
// 2-D DCT/IDCT = in-lane 8-pt transforms + in-register 8x8 transposes via DPP
// (no LDS traffic for the matmuls). Quantizer round() decisions are kept
// f64-faithful via a rare rescue that recomputes the coefficient from global.

#define LEVELD 0.5019607843137255
#define LEVELF 0.5019607843137255f
#define BAND   1.5e-4f

__device__ const double DMATD[64] = {
  0.3535533905932738,  0.3535533905932738,  0.3535533905932738,  0.3535533905932738,
  0.3535533905932738,  0.3535533905932738,  0.3535533905932738,  0.3535533905932738,
  0.4903926402016152,  0.4157348061512726,  0.2777851165098011,  0.0975451610080641,
 -0.0975451610080641, -0.2777851165098011, -0.4157348061512726, -0.4903926402016152,
  0.4619397662556434,  0.1913417161825449, -0.1913417161825449, -0.4619397662556434,
 -0.4619397662556434, -0.1913417161825449,  0.1913417161825449,  0.4619397662556434,
  0.4157348061512726, -0.0975451610080641, -0.4903926402016152, -0.2777851165098011,
  0.2777851165098011,  0.4903926402016152,  0.0975451610080641, -0.4157348061512726,
  0.3535533905932738, -0.3535533905932738, -0.3535533905932738,  0.3535533905932738,
  0.3535533905932738, -0.3535533905932738, -0.3535533905932738,  0.3535533905932738,
  0.2777851165098011, -0.4903926402016152,  0.0975451610080641,  0.4157348061512726,
 -0.4157348061512726, -0.0975451610080641,  0.4903926402016152, -0.2777851165098011,
  0.1913417161825449, -0.4619397662556434,  0.4619397662556434, -0.1913417161825449,
 -0.1913417161825449,  0.4619397662556434, -0.4619397662556434,  0.1913417161825449,
  0.0975451610080641, -0.2777851165098011,  0.4157348061512726, -0.4903926402016152,
  0.4903926402016152, -0.4157348061512726,  0.2777851165098011, -0.0975451610080641
};

static constexpr float DF[8][8] = {
  { 0.35355339059327373f, 0.35355339059327373f, 0.35355339059327373f, 0.35355339059327373f,
    0.35355339059327373f, 0.35355339059327373f, 0.35355339059327373f, 0.35355339059327373f },
  { 0.49039264020161522f, 0.41573480615127262f, 0.27778511650980114f, 0.09754516100806413f,
   -0.09754516100806413f,-0.27778511650980114f,-0.41573480615127262f,-0.49039264020161522f },
  { 0.46193976625564337f, 0.19134171618254489f,-0.19134171618254489f,-0.46193976625564337f,
   -0.46193976625564337f,-0.19134171618254489f, 0.19134171618254489f, 0.46193976625564337f },
  { 0.41573480615127262f,-0.09754516100806413f,-0.49039264020161522f,-0.27778511650980114f,
    0.27778511650980114f, 0.49039264020161522f, 0.09754516100806413f,-0.41573480615127262f },
  { 0.35355339059327373f,-0.35355339059327373f,-0.35355339059327373f, 0.35355339059327373f,
    0.35355339059327373f,-0.35355339059327373f,-0.35355339059327373f, 0.35355339059327373f },
  { 0.27778511650980114f,-0.49039264020161522f, 0.09754516100806413f, 0.41573480615127262f,
   -0.41573480615127262f,-0.09754516100806413f, 0.49039264020161522f,-0.27778511650980114f },
  { 0.19134171618254489f,-0.46193976625564337f, 0.46193976625564337f,-0.19134171618254489f,
   -0.19134171618254489f, 0.46193976625564337f,-0.46193976625564337f, 0.19134171618254489f },
  { 0.09754516100806413f,-0.27778511650980114f, 0.41573480615127262f,-0.49039264020161522f,
    0.49039264020161522f,-0.41573480615127262f, 0.27778511650980114f,-0.09754516100806413f }
};

// ---- DPP cross-lane helpers (VALU only, no DS pipe) ----
__device__ __forceinline__ float dpp_xor1(float x) {  // quad_perm(1,0,3,2)
  return __int_as_float(__builtin_amdgcn_mov_dpp(__float_as_int(x), 0xB1, 0xF, 0xF, true));
}
__device__ __forceinline__ float dpp_xor2(float x) {  // quad_perm(2,3,0,1)
  return __int_as_float(__builtin_amdgcn_mov_dpp(__float_as_int(x), 0x4E, 0xF, 0xF, true));
}
__device__ __forceinline__ float dpp_xor4(float x) {  // half_mirror (xor7) o quad mirror (xor3)
  int t = __builtin_amdgcn_mov_dpp(__float_as_int(x), 0x141, 0xF, 0xF, true);
  return __int_as_float(__builtin_amdgcn_mov_dpp(t, 0x1B, 0xF, 0xF, true));
}

// in-register 8x8 transpose across the 8 lanes of a group; v[j]@p -> v[p]@j
__device__ __forceinline__ void transpose8(float v[8], int p) {
  { float t[8];
    #pragma unroll
    for (int j = 0; j < 8; ++j) t[j] = dpp_xor1(v[j ^ 1]);
    const bool lb = (p & 1) != 0;
    #pragma unroll
    for (int j = 0; j < 8; ++j) v[j] = (lb == ((j & 1) != 0)) ? v[j] : t[j];
  }
  { float t[8];
    #pragma unroll
    for (int j = 0; j < 8; ++j) t[j] = dpp_xor2(v[j ^ 2]);
    const bool lb = (p & 2) != 0;
    #pragma unroll
    for (int j = 0; j < 8; ++j) v[j] = (lb == ((j & 2) != 0)) ? v[j] : t[j];
  }
  { float t[8];
    #pragma unroll
    for (int j = 0; j < 8; ++j) t[j] = dpp_xor4(v[j ^ 4]);
    const bool lb = (p & 4) != 0;
    #pragma unroll
    for (int j = 0; j < 8; ++j) v[j] = (lb == ((j & 4) != 0)) ? v[j] : t[j];
  }
}

// o[j] = sum_c D[j][c] * x[c]   (forward 1-D DCT)
__device__ __forceinline__ void fdct8(const float x[8], float o[8]) {
  #pragma unroll
  for (int j = 0; j < 8; ++j) {
    float s = DF[j][0] * x[0];
    #pragma unroll
    for (int c = 1; c < 8; ++c) s = fmaf(DF[j][c], x[c], s);
    o[j] = s;
  }
}
// o[j] = sum_k D[k][j] * x[k]   (inverse 1-D DCT)
__device__ __forceinline__ void idct8(const float x[8], float o[8]) {
  #pragma unroll
  for (int j = 0; j < 8; ++j) {
    float s = DF[0][j] * x[0];
    #pragma unroll
    for (int k = 1; k < 8; ++k) s = fmaf(DF[k][j], x[k], s);
    o[j] = s;
  }
}

// f64 recompute of coefficient (i,j) of block g from global pixels (rare)
__device__ float rescue_elem(const float* __restrict__ quant,
                             const float* __restrict__ tb,
                             int g, int i, int j) {
  double acc = 0.0;
  if (g < 4) {
    const float* px = tb + (size_t)((g >> 1) * 8) * 512 + (g & 1) * 8;
    #pragma unroll 1
    for (int k = 0; k < 8; ++k) {
      double e = 0.0;
      #pragma unroll 1
      for (int l = 0; l < 8; ++l) {
        size_t off = (size_t)k * 512 + l;
        double rr = (double)px[off];
        double gg = (double)px[262144 + off];
        double bb = (double)px[524288 + off];
        double y = 0.299 * rr + 0.587 * gg + 0.114 * bb;
        y = fmin(fmax(y, 0.0), 1.0) - LEVELD;
        e += y * DMATD[j * 8 + l];
      }
      acc += DMATD[i * 8 + k] * e;
    }
  } else {
    const double c0 = (g == 4) ? -0.168735892 : 0.5;
    const double c1 = (g == 4) ? -0.331264108 : -0.418687589;
    const double c2 = (g == 4) ?  0.5         : -0.081312411;
    #pragma unroll 1
    for (int k = 0; k < 8; ++k) {
      double e = 0.0;
      #pragma unroll 1
      for (int l = 0; l < 8; ++l) {
        double m = 0.0;
        #pragma unroll
        for (int dr = 0; dr < 2; ++dr) {
          #pragma unroll
          for (int dc = 0; dc < 2; ++dc) {
            size_t off = (size_t)(2 * k + dr) * 512 + (2 * l + dc);
            double rr = (double)tb[off];
            double gg = (double)tb[262144 + off];
            double bb = (double)tb[524288 + off];
            double v = c0 * rr + c1 * gg + c2 * bb;
            m += fmin(fmax(v + LEVELD, 0.0), 1.0) - LEVELD;
          }
        }
        e += (0.25 * m) * DMATD[j * 8 + l];
      }
      acc += DMATD[i * 8 + k] * e;
    }
  }
  double qd = rint((double)quant[i * 8 + j] * 255.0) / 255.0;
  return (float)rint(acc / qd);
}

__global__ __launch_bounds__(256) void jpeg_fused(
    const float* __restrict__ in, const float* __restrict__ quant,
    float* __restrict__ out)
{
  __shared__ float CH[4][136];   // per wave: [cb 68 | cr 68] (68 = 8x8 + pad)

  const int t    = threadIdx.x;
  const int wv   = t >> 6;
  const int lane = t & 63;
  const int g    = lane >> 3;
  const int p    = lane & 7;

  const int tile = blockIdx.x * 4 + wv;
  const int img  = tile >> 10;
  const int trow = (tile >> 5) & 31;
  const int tcol = tile & 31;
  const size_t tbase = (size_t)img * 786432 + (size_t)(trow * 16) * 512 + tcol * 16;
  const float* tb = in + tbase;
  float* CHw = &CH[wv][0];

  // f64-exact quant row for this lane's column index p
  float qv[8], rq[8];
  #pragma unroll
  for (int i = 0; i < 8; ++i) {
    double qd = rint((double)quant[i * 8 + p] * 255.0) / 255.0;
    qv[i] = (float)qd;
    rq[i] = 1.0f / qv[i];
  }

  float x[8];
  if (g < 4) {
    // 8 pixels: row p of Y block g, straight into registers
    const float* pb = tb + (size_t)((g >> 1) * 8 + p) * 512 + (g & 1) * 8;
    const float4 r0 = *(const float4*)(pb);
    const float4 r1 = *(const float4*)(pb + 4);
    const float4 g0 = *(const float4*)(pb + 262144);
    const float4 g1 = *(const float4*)(pb + 262144 + 4);
    const float4 b0 = *(const float4*)(pb + 524288);
    const float4 b1 = *(const float4*)(pb + 524288 + 4);
    const float RL[8] = {r0.x, r0.y, r0.z, r0.w, r1.x, r1.y, r1.z, r1.w};
    const float GL[8] = {g0.x, g0.y, g0.z, g0.w, g1.x, g1.y, g1.z, g1.w};
    const float BL[8] = {b0.x, b0.y, b0.z, b0.w, b1.x, b1.y, b1.z, b1.w};

    float cb[8], cr[8];
    #pragma unroll
    for (int l = 0; l < 8; ++l) {
      const float rr = RL[l], gg = GL[l], bb = BL[l];
      float y   =  0.299f       * rr + 0.587f       * gg + 0.114f       * bb;
      float cb_ = -0.168735892f * rr - 0.331264108f * gg + 0.5f         * bb;
      float cr_ =  0.5f         * rr - 0.418687589f * gg - 0.081312411f * bb;
      x[l]  = fminf(fmaxf(y,           0.0f), 1.0f) - LEVELF;
      cb[l] = fminf(fmaxf(cb_ + LEVELF, 0.0f), 1.0f) - LEVELF;
      cr[l] = fminf(fmaxf(cr_ + LEVELF, 0.0f), 1.0f) - LEVELF;
    }
    // 2x2 chroma mean: horizontal pairs in-lane, vertical pair via DPP xor1
    float ch[4];
    #pragma unroll
    for (int j = 0; j < 4; ++j) {
      float cbh = cb[2 * j] + cb[2 * j + 1];
      float crh = cr[2 * j] + cr[2 * j + 1];
      float cbv = cbh + dpp_xor1(cbh);
      float crv = crh + dpp_xor1(crh);
      ch[j] = 0.25f * ((p & 1) ? crv : cbv);   // even lanes: cb, odd: cr
    }
    // stage chroma quadrant row: block row (g>>1)*4 + p/2, cols (g&1)*4..+3
    float* dst = CHw + (p & 1) * 68 + ((g >> 1) * 4 + (p >> 1)) * 8 + (g & 1) * 4;
    *(float4*)dst = make_float4(ch[0], ch[1], ch[2], ch[3]);
  }
  __builtin_amdgcn_wave_barrier();

  if (g >= 4) {   // chroma (and ride-along g=6,7): row p of Cb/Cr from LDS
    const float* src = CHw + (g & 1) * 68 + p * 8;
    const float4 a = *(const float4*)(src);
    const float4 b = *(const float4*)(src + 4);
    x[0] = a.x; x[1] = a.y; x[2] = a.z; x[3] = a.w;
    x[4] = b.x; x[5] = b.y; x[6] = b.z; x[7] = b.w;
  }
  __builtin_amdgcn_wave_barrier();

  // ---- 2-D DCT: U = X*D^T (rows), transpose, S = D*U (cols) ----
  float u[8];
  fdct8(x, u);
  transpose8(u, p);
  float s[8];
  fdct8(u, s);

  // ---- quantize-round-dequant with f64 rescue near half-integers ----
  #pragma unroll
  for (int i = 0; i < 8; ++i) {
    const float tt = s[i] * rq[i];
    float rt = rintf(tt);
    if (g < 6 && fabsf(tt - rt) > 0.5f - BAND)
      rt = rescue_elem(quant, tb, g, i, p);
    s[i] = rt * qv[i];
  }

  // ---- 2-D IDCT: V = D^T*Shat (cols), transpose, R = V*D (rows) ----
  float v[8];
  idct8(s, v);
  transpose8(v, p);
  float r[8];
  idct8(v, r);

  // chroma results back to LDS for upsampling
  if ((g & 6) == 4) {   // g == 4 or 5
    float* dst = CHw + (g & 1) * 68 + p * 8;
    *(float4*)(dst)     = make_float4(r[0], r[1], r[2], r[3]);
    *(float4*)(dst + 4) = make_float4(r[4], r[5], r[6], r[7]);
  }
  __builtin_amdgcn_wave_barrier();

  if (g < 4) {
    const float* cbp = CHw + ((g >> 1) * 4 + (p >> 1)) * 8 + (g & 1) * 4;
    const float4 cb4 = *(const float4*)(cbp);
    const float4 cr4 = *(const float4*)(cbp + 68);
    const float cbl[4] = {cb4.x, cb4.y, cb4.z, cb4.w};
    const float crl[4] = {cr4.x, cr4.y, cr4.z, cr4.w};

    float R_[8], G_[8], B_[8];
    #pragma unroll
    for (int l = 0; l < 8; ++l) {
      const float y2 = r[l] + LEVELF;        // chroma LEVEL offsets cancel
      const float cbv = cbl[l >> 1];
      const float crv = crl[l >> 1];
      float ro = fmaf(1.402f, crv, y2);
      float go = y2 - 0.344136286f * cbv - 0.714136286f * crv;
      float bo = fmaf(1.772f, cbv, y2);
      R_[l] = fminf(fmaxf(ro, 0.0f), 1.0f);
      G_[l] = fminf(fmaxf(go, 0.0f), 1.0f);
      B_[l] = fminf(fmaxf(bo, 0.0f), 1.0f);
    }
    float* ob = out + tbase + (size_t)((g >> 1) * 8 + p) * 512 + (g & 1) * 8;
    *(float4*)(ob)              = make_float4(R_[0], R_[1], R_[2], R_[3]);
    *(float4*)(ob + 4)          = make_float4(R_[4], R_[5], R_[6], R_[7]);
    *(float4*)(ob + 262144)     = make_float4(G_[0], G_[1], G_[2], G_[3]);
    *(float4*)(ob + 262144 + 4) = make_float4(G_[4], G_[5], G_[6], G_[7]);
    *(float4*)(ob + 524288)     = make_float4(B_[0], B_[1], B_[2], B_[3]);
    *(float4*)(ob + 524288 + 4) = make_float4(B_[4], B_[5], B_[6], B_[7]);
  }
}

extern "C" void kernel_launch(void* const* d_in, const int* in_sizes, int n_in,
                              void* d_out, int out_size, void* d_ws, size_t ws_size,
                              hipStream_t stream) {
  const float* in    = (const float*)d_in[0];
  const float* quant = (const float*)d_in[1];  // only quantize[0] (64 floats) used
  float* out = (float*)d_out;

  const int n_blocks = 32 * 32 * 32 / 4;   // one 16x16 tile per wave, 4 waves/block
  jpeg_fused<<<dim3(n_blocks), dim3(256), 0, stream>>>(in, quant, out);
}

// Round 5
// 97.331 us; speedup vs baseline: 1.0012x; 1.0012x over previous
//
#include <hip/hip_runtime.h>
#include <cmath>

// JPEG layer, fully fused, one wave per 16x16 tile.
// Lane (g,p): g = lane>>3 (block slot), p = lane&7 (row).
//   g 0..3 : Y 8x8 blocks (pixels loaded straight into registers)
//   g 4,5  : Cb / Cr blocks (staged through a tiny per-wave LDS buffer)
//   g 6,7  : ride along on the transform (masked from rescue/stores)
// 2-D DCT/IDCT = in-lane 8-pt transforms + in-register 8x8 transposes via DPP
// (no LDS traffic for the matmuls). Quantizer round() decisions are kept
// f64-faithful via a rare rescue that recomputes the coefficient from global.

#define LEVELD 0.5019607843137255
#define LEVELF 0.5019607843137255f
#define BAND   1.5e-4f

__device__ const double DMATD[64] = {
  0.3535533905932738,  0.3535533905932738,  0.3535533905932738,  0.3535533905932738,
  0.3535533905932738,  0.3535533905932738,  0.3535533905932738,  0.3535533905932738,
  0.4903926402016152,  0.4157348061512726,  0.2777851165098011,  0.0975451610080641,
 -0.0975451610080641, -0.2777851165098011, -0.4157348061512726, -0.4903926402016152,
  0.4619397662556434,  0.1913417161825449, -0.1913417161825449, -0.4619397662556434,
 -0.4619397662556434, -0.1913417161825449,  0.1913417161825449,  0.4619397662556434,
  0.4157348061512726, -0.0975451610080641, -0.4903926402016152, -0.2777851165098011,
  0.2777851165098011,  0.4903926402016152,  0.0975451610080641, -0.4157348061512726,
  0.3535533905932738, -0.3535533905932738, -0.3535533905932738,  0.3535533905932738,
  0.3535533905932738, -0.3535533905932738, -0.3535533905932738,  0.3535533905932738,
  0.2777851165098011, -0.4903926402016152,  0.0975451610080641,  0.4157348061512726,
 -0.4157348061512726, -0.0975451610080641,  0.4903926402016152, -0.2777851165098011,
  0.1913417161825449, -0.4619397662556434,  0.4619397662556434, -0.1913417161825449,
 -0.1913417161825449,  0.4619397662556434, -0.4619397662556434,  0.1913417161825449,
  0.0975451610080641, -0.2777851165098011,  0.4157348061512726, -0.4903926402016152,
  0.4903926402016152, -0.4157348061512726,  0.2777851165098011, -0.0975451610080641
};

static constexpr float DF[8][8] = {
  { 0.35355339059327373f, 0.35355339059327373f, 0.35355339059327373f, 0.35355339059327373f,
    0.35355339059327373f, 0.35355339059327373f, 0.35355339059327373f, 0.35355339059327373f },
  { 0.49039264020161522f, 0.41573480615127262f, 0.27778511650980114f, 0.09754516100806413f,
   -0.09754516100806413f,-0.27778511650980114f,-0.41573480615127262f,-0.49039264020161522f },
  { 0.46193976625564337f, 0.19134171618254489f,-0.19134171618254489f,-0.46193976625564337f,
   -0.46193976625564337f,-0.19134171618254489f, 0.19134171618254489f, 0.46193976625564337f },
  { 0.41573480615127262f,-0.09754516100806413f,-0.49039264020161522f,-0.27778511650980114f,
    0.27778511650980114f, 0.49039264020161522f, 0.09754516100806413f,-0.41573480615127262f },
  { 0.35355339059327373f,-0.35355339059327373f,-0.35355339059327373f, 0.35355339059327373f,
    0.35355339059327373f,-0.35355339059327373f,-0.35355339059327373f, 0.35355339059327373f },
  { 0.27778511650980114f,-0.49039264020161522f, 0.09754516100806413f, 0.41573480615127262f,
   -0.41573480615127262f,-0.09754516100806413f, 0.49039264020161522f,-0.27778511650980114f },
  { 0.19134171618254489f,-0.46193976625564337f, 0.46193976625564337f,-0.19134171618254489f,
   -0.19134171618254489f, 0.46193976625564337f,-0.46193976625564337f, 0.19134171618254489f },
  { 0.09754516100806413f,-0.27778511650980114f, 0.41573480615127262f,-0.49039264020161522f,
    0.49039264020161522f,-0.41573480615127262f, 0.27778511650980114f,-0.09754516100806413f }
};

// ---- DPP cross-lane helpers (VALU only, no DS pipe) ----
__device__ __forceinline__ float dpp_xor1(float x) {  // quad_perm(1,0,3,2)
  return __int_as_float(__builtin_amdgcn_mov_dpp(__float_as_int(x), 0xB1, 0xF, 0xF, true));
}
__device__ __forceinline__ float dpp_xor2(float x) {  // quad_perm(2,3,0,1)
  return __int_as_float(__builtin_amdgcn_mov_dpp(__float_as_int(x), 0x4E, 0xF, 0xF, true));
}
__device__ __forceinline__ float dpp_xor4(float x) {  // half_mirror (xor7) o quad mirror (xor3)
  int t = __builtin_amdgcn_mov_dpp(__float_as_int(x), 0x141, 0xF, 0xF, true);
  return __int_as_float(__builtin_amdgcn_mov_dpp(t, 0x1B, 0xF, 0xF, true));
}

// in-register 8x8 transpose across the 8 lanes of a group; v[j]@p -> v[p]@j
__device__ __forceinline__ void transpose8(float v[8], int p) {
  { float t[8];
    #pragma unroll
    for (int j = 0; j < 8; ++j) t[j] = dpp_xor1(v[j ^ 1]);
    const bool lb = (p & 1) != 0;
    #pragma unroll
    for (int j = 0; j < 8; ++j) v[j] = (lb == ((j & 1) != 0)) ? v[j] : t[j];
  }
  { float t[8];
    #pragma unroll
    for (int j = 0; j < 8; ++j) t[j] = dpp_xor2(v[j ^ 2]);
    const bool lb = (p & 2) != 0;
    #pragma unroll
    for (int j = 0; j < 8; ++j) v[j] = (lb == ((j & 2) != 0)) ? v[j] : t[j];
  }
  { float t[8];
    #pragma unroll
    for (int j = 0; j < 8; ++j) t[j] = dpp_xor4(v[j ^ 4]);
    const bool lb = (p & 4) != 0;
    #pragma unroll
    for (int j = 0; j < 8; ++j) v[j] = (lb == ((j & 4) != 0)) ? v[j] : t[j];
  }
}

// o[j] = sum_c D[j][c] * x[c]   (forward 1-D DCT)
__device__ __forceinline__ void fdct8(const float x[8], float o[8]) {
  #pragma unroll
  for (int j = 0; j < 8; ++j) {
    float s = DF[j][0] * x[0];
    #pragma unroll
    for (int c = 1; c < 8; ++c) s = fmaf(DF[j][c], x[c], s);
    o[j] = s;
  }
}
// o[j] = sum_k D[k][j] * x[k]   (inverse 1-D DCT)
__device__ __forceinline__ void idct8(const float x[8], float o[8]) {
  #pragma unroll
  for (int j = 0; j < 8; ++j) {
    float s = DF[0][j] * x[0];
    #pragma unroll
    for (int k = 1; k < 8; ++k) s = fmaf(DF[k][j], x[k], s);
    o[j] = s;
  }
}

// f64 recompute of coefficient (i,j) of block g from global pixels (rare)
__device__ float rescue_elem(const float* __restrict__ quant,
                             const float* __restrict__ tb,
                             int g, int i, int j) {
  double acc = 0.0;
  if (g < 4) {
    const float* px = tb + (size_t)((g >> 1) * 8) * 512 + (g & 1) * 8;
    #pragma unroll 1
    for (int k = 0; k < 8; ++k) {
      double e = 0.0;
      #pragma unroll 1
      for (int l = 0; l < 8; ++l) {
        size_t off = (size_t)k * 512 + l;
        double rr = (double)px[off];
        double gg = (double)px[262144 + off];
        double bb = (double)px[524288 + off];
        double y = 0.299 * rr + 0.587 * gg + 0.114 * bb;
        y = fmin(fmax(y, 0.0), 1.0) - LEVELD;
        e += y * DMATD[j * 8 + l];
      }
      acc += DMATD[i * 8 + k] * e;
    }
  } else {
    const double c0 = (g == 4) ? -0.168735892 : 0.5;
    const double c1 = (g == 4) ? -0.331264108 : -0.418687589;
    const double c2 = (g == 4) ?  0.5         : -0.081312411;
    #pragma unroll 1
    for (int k = 0; k < 8; ++k) {
      double e = 0.0;
      #pragma unroll 1
      for (int l = 0; l < 8; ++l) {
        double m = 0.0;
        #pragma unroll
        for (int dr = 0; dr < 2; ++dr) {
          #pragma unroll
          for (int dc = 0; dc < 2; ++dc) {
            size_t off = (size_t)(2 * k + dr) * 512 + (2 * l + dc);
            double rr = (double)tb[off];
            double gg = (double)tb[262144 + off];
            double bb = (double)tb[524288 + off];
            double v = c0 * rr + c1 * gg + c2 * bb;
            m += fmin(fmax(v + LEVELD, 0.0), 1.0) - LEVELD;
          }
        }
        e += (0.25 * m) * DMATD[j * 8 + l];
      }
      acc += DMATD[i * 8 + k] * e;
    }
  }
  double qd = rint((double)quant[i * 8 + j] * 255.0) / 255.0;
  return (float)rint(acc / qd);
}

__global__ __launch_bounds__(256) void jpeg_fused(
    const float* __restrict__ in, const float* __restrict__ quant,
    float* __restrict__ out)
{
  __shared__ float CH[4][136];   // per wave: [cb 68 | cr 68] (68 = 8x8 + pad)

  const int t    = threadIdx.x;
  const int wv   = t >> 6;
  const int lane = t & 63;
  const int g    = lane >> 3;
  const int p    = lane & 7;

  const int tile = blockIdx.x * 4 + wv;
  const int img  = tile >> 10;
  const int trow = (tile >> 5) & 31;
  const int tcol = tile & 31;
  const size_t tbase = (size_t)img * 786432 + (size_t)(trow * 16) * 512 + tcol * 16;
  const float* tb = in + tbase;
  float* CHw = &CH[wv][0];

  // f64-exact quant row for this lane's column index p
  float qv[8], rq[8];
  #pragma unroll
  for (int i = 0; i < 8; ++i) {
    double qd = rint((double)quant[i * 8 + p] * 255.0) / 255.0;
    qv[i] = (float)qd;
    rq[i] = 1.0f / qv[i];
  }

  float x[8];
  if (g < 4) {
    // 8 pixels: row p of Y block g, straight into registers
    const float* pb = tb + (size_t)((g >> 1) * 8 + p) * 512 + (g & 1) * 8;
    const float4 r0 = *(const float4*)(pb);
    const float4 r1 = *(const float4*)(pb + 4);
    const float4 g0 = *(const float4*)(pb + 262144);
    const float4 g1 = *(const float4*)(pb + 262144 + 4);
    const float4 b0 = *(const float4*)(pb + 524288);
    const float4 b1 = *(const float4*)(pb + 524288 + 4);
    const float RL[8] = {r0.x, r0.y, r0.z, r0.w, r1.x, r1.y, r1.z, r1.w};
    const float GL[8] = {g0.x, g0.y, g0.z, g0.w, g1.x, g1.y, g1.z, g1.w};
    const float BL[8] = {b0.x, b0.y, b0.z, b0.w, b1.x, b1.y, b1.z, b1.w};

    float cb[8], cr[8];
    #pragma unroll
    for (int l = 0; l < 8; ++l) {
      const float rr = RL[l], gg = GL[l], bb = BL[l];
      float y   =  0.299f       * rr + 0.587f       * gg + 0.114f       * bb;
      float cb_ = -0.168735892f * rr - 0.331264108f * gg + 0.5f         * bb;
      float cr_ =  0.5f         * rr - 0.418687589f * gg - 0.081312411f * bb;
      x[l]  = fminf(fmaxf(y,           0.0f), 1.0f) - LEVELF;
      cb[l] = fminf(fmaxf(cb_ + LEVELF, 0.0f), 1.0f) - LEVELF;
      cr[l] = fminf(fmaxf(cr_ + LEVELF, 0.0f), 1.0f) - LEVELF;
    }
    // 2x2 chroma mean: horizontal pairs in-lane, vertical pair via DPP xor1
    float ch[4];
    #pragma unroll
    for (int j = 0; j < 4; ++j) {
      float cbh = cb[2 * j] + cb[2 * j + 1];
      float crh = cr[2 * j] + cr[2 * j + 1];
      float cbv = cbh + dpp_xor1(cbh);
      float crv = crh + dpp_xor1(crh);
      ch[j] = 0.25f * ((p & 1) ? crv : cbv);   // even lanes: cb, odd: cr
    }
    // stage chroma quadrant row: block row (g>>1)*4 + p/2, cols (g&1)*4..+3
    float* dst = CHw + (p & 1) * 68 + ((g >> 1) * 4 + (p >> 1)) * 8 + (g & 1) * 4;
    *(float4*)dst = make_float4(ch[0], ch[1], ch[2], ch[3]);
  }
  __builtin_amdgcn_wave_barrier();

  if (g >= 4) {   // chroma (and ride-along g=6,7): row p of Cb/Cr from LDS
    const float* src = CHw + (g & 1) * 68 + p * 8;
    const float4 a = *(const float4*)(src);
    const float4 b = *(const float4*)(src + 4);
    x[0] = a.x; x[1] = a.y; x[2] = a.z; x[3] = a.w;
    x[4] = b.x; x[5] = b.y; x[6] = b.z; x[7] = b.w;
  }
  __builtin_amdgcn_wave_barrier();

  // ---- 2-D DCT: U = X*D^T (rows), transpose, S = D*U (cols) ----
  float u[8];
  fdct8(x, u);
  transpose8(u, p);
  float s[8];
  fdct8(u, s);

  // ---- quantize-round-dequant with f64 rescue near half-integers ----
  #pragma unroll
  for (int i = 0; i < 8; ++i) {
    const float tt = s[i] * rq[i];
    float rt = rintf(tt);
    if (g < 6 && fabsf(tt - rt) > 0.5f - BAND)
      rt = rescue_elem(quant, tb, g, i, p);
    s[i] = rt * qv[i];
  }

  // ---- 2-D IDCT: V = D^T*Shat (cols), transpose, R = V*D (rows) ----
  float v[8];
  idct8(s, v);
  transpose8(v, p);
  float r[8];
  idct8(v, r);

  // chroma results back to LDS for upsampling
  if ((g & 6) == 4) {   // g == 4 or 5
    float* dst = CHw + (g & 1) * 68 + p * 8;
    *(float4*)(dst)     = make_float4(r[0], r[1], r[2], r[3]);
    *(float4*)(dst + 4) = make_float4(r[4], r[5], r[6], r[7]);
  }
  __builtin_amdgcn_wave_barrier();

  if (g < 4) {
    const float* cbp = CHw + ((g >> 1) * 4 + (p >> 1)) * 8 + (g & 1) * 4;
    const float4 cb4 = *(const float4*)(cbp);
    const float4 cr4 = *(const float4*)(cbp + 68);
    const float cbl[4] = {cb4.x, cb4.y, cb4.z, cb4.w};
    const float crl[4] = {cr4.x, cr4.y, cr4.z, cr4.w};

    float R_[8], G_[8], B_[8];
    #pragma unroll
    for (int l = 0; l < 8; ++l) {
      const float y2 = r[l] + LEVELF;        // chroma LEVEL offsets cancel
      const float cbv = cbl[l >> 1];
      const float crv = crl[l >> 1];
      float ro = fmaf(1.402f, crv, y2);
      float go = y2 - 0.344136286f * cbv - 0.714136286f * crv;
      float bo = fmaf(1.772f, cbv, y2);
      R_[l] = fminf(fmaxf(ro, 0.0f), 1.0f);
      G_[l] = fminf(fmaxf(go, 0.0f), 1.0f);
      B_[l] = fminf(fmaxf(bo, 0.0f), 1.0f);
    }
    float* ob = out + tbase + (size_t)((g >> 1) * 8 + p) * 512 + (g & 1) * 8;
    *(float4*)(ob)              = make_float4(R_[0], R_[1], R_[2], R_[3]);
    *(float4*)(ob + 4)          = make_float4(R_[4], R_[5], R_[6], R_[7]);
    *(float4*)(ob + 262144)     = make_float4(G_[0], G_[1], G_[2], G_[3]);
    *(float4*)(ob + 262144 + 4) = make_float4(G_[4], G_[5], G_[6], G_[7]);
    *(float4*)(ob + 524288)     = make_float4(B_[0], B_[1], B_[2], B_[3]);
    *(float4*)(ob + 524288 + 4) = make_float4(B_[4], B_[5], B_[6], B_[7]);
  }
}

extern "C" void kernel_launch(void* const* d_in, const int* in_sizes, int n_in,
                              void* d_out, int out_size, void* d_ws, size_t ws_size,
                              hipStream_t stream) {
  const float* in    = (const float*)d_in[0];
  const float* quant = (const float*)d_in[1];  // only quantize[0] (64 floats) used
  float* out = (float*)d_out;

  const int n_blocks = 32 * 32 * 32 / 4;   // one 16x16 tile per wave, 4 waves/block
  jpeg_fused<<<dim3(n_blocks), dim3(256), 0, stream>>>(in, quant, out);
}